// Round 9
// baseline (261.942 us; speedup 1.0000x reference)
//
#include <hip/hip_runtime.h>

typedef __attribute__((ext_vector_type(8))) short bf16x8;
typedef __attribute__((ext_vector_type(4))) short bf16x4;
typedef __attribute__((ext_vector_type(4))) float f32x4;

__device__ __forceinline__ unsigned short f2bf(float x){
  unsigned u = __float_as_uint(x);
  u = (u + 0x7fffu + ((u >> 16) & 1u)) >> 16;
  return (unsigned short)u;
}

__device__ __forceinline__ bf16x8 cvtpack8(float4 a, float4 b){
  union { bf16x8 v; unsigned short u[8]; } p;
  p.u[0] = f2bf(a.x); p.u[1] = f2bf(a.y); p.u[2] = f2bf(a.z); p.u[3] = f2bf(a.w);
  p.u[4] = f2bf(b.x); p.u[5] = f2bf(b.y); p.u[6] = f2bf(b.z); p.u[7] = f2bf(b.w);
  return p.v;
}

// async global->LDS, 16B/lane: LDS dest = wave-uniform base + lane*16
__device__ __forceinline__ void gload16(const void* g, void* l){
  __builtin_amdgcn_global_load_lds(
      (const __attribute__((address_space(1))) unsigned int*)g,
      (__attribute__((address_space(3))) unsigned int*)l, 16, 0, 0);
}

// ---- B tile format (bf16): tile sg covers k in [sg*32, sg*32+32), 16KB:
//   elem = sg*8192 + ((k>>3)&3)*2048 + c*8 + (k&7)      (c in [0,256))
// Contiguous per tile -> verbatim global_load_lds staging; ds_read_b128 of a
// (c-run, k-chunk) fragment is contiguous 256B per 16 lanes (conflict-free).

// ---------------- zero init ----------------
__global__ __launch_bounds__(256) void kzero(float* __restrict__ G0, float* __restrict__ n2){
  int b = blockIdx.x;
  if (b < 256) G0[b * 256 + threadIdx.x] = 0.0f;
  else if (threadIdx.x == 0) *n2 = 0.0f;
}

// ---------------- Bjorck (polar factor) small kernels ----------------

__global__ __launch_bounds__(256) void knorm(const float* __restrict__ wt, float* __restrict__ n2){
  int t = blockIdx.x * 256 + threadIdx.x;
  float4 v = reinterpret_cast<const float4*>(wt)[t];
  float s = v.x*v.x + v.y*v.y + v.z*v.z + v.w*v.w;
  #pragma unroll
  for (int o = 32; o > 0; o >>= 1) s += __shfl_down(s, o, 64);
  __shared__ float red[4];
  if ((threadIdx.x & 63) == 0) red[threadIdx.x >> 6] = s;
  __syncthreads();
  if (threadIdx.x == 0) atomicAdd(n2, red[0] + red[1] + red[2] + red[3]);
}

__global__ __launch_bounds__(256) void kinit(const float* __restrict__ wt, const float* __restrict__ n2,
                                             float* __restrict__ W){
  int c = blockIdx.x;
  int r = threadIdx.x;
  float s = rsqrtf(*n2) * (1.0f / 0.3f);
  W[(size_t)r * 256 + c]         = wt[(size_t)c * 512 + r] * s;
  W[(size_t)(r + 256) * 256 + c] = wt[(size_t)c * 512 + r + 256] * s;
}

// G += partial(W^T W): grid (8 j, 8 i, 8 k-parts), 32x32 tile, k-range 64
__global__ __launch_bounds__(256) void kgram2(const float* __restrict__ W, float* __restrict__ G){
  __shared__ __align__(16) float Wi[64][32];
  __shared__ __align__(16) float Wj[64][32];
  const int t = threadIdx.x;
  const int i0 = blockIdx.y * 32, j0 = blockIdx.x * 32, k0 = blockIdx.z * 64;
  const int lr = t >> 3, lc = (t & 7) * 4;
  #pragma unroll
  for (int p = 0; p < 2; ++p){
    int r = lr + p * 32;
    *reinterpret_cast<float4*>(&Wi[r][lc]) =
        *reinterpret_cast<const float4*>(&W[(size_t)(k0 + r) * 256 + i0 + lc]);
    *reinterpret_cast<float4*>(&Wj[r][lc]) =
        *reinterpret_cast<const float4*>(&W[(size_t)(k0 + r) * 256 + j0 + lc]);
  }
  __syncthreads();
  const int tx = t & 31, iy = t >> 5;
  float g0 = 0, g1 = 0, g2 = 0, g3 = 0;
  #pragma unroll 8
  for (int k = 0; k < 64; ++k){
    float wj = Wj[k][tx];
    float4 wi = *reinterpret_cast<const float4*>(&Wi[k][iy * 4]);
    g0 = fmaf(wi.x, wj, g0); g1 = fmaf(wi.y, wj, g1);
    g2 = fmaf(wi.z, wj, g2); g3 = fmaf(wi.w, wj, g3);
  }
  float* gp = &G[(size_t)(i0 + iy * 4) * 256 + j0 + tx];
  atomicAdd(gp,       g0); atomicAdd(gp + 256, g1);
  atomicAdd(gp + 512, g2); atomicAdd(gp + 768, g3);
}

// W <- ca*W + cb*(W G) + cc*(W G) G ; zeroes Gnext; last: emit WT2 in B tile format
__global__ __launch_bounds__(512) void kupdate2(float* __restrict__ W, const float* __restrict__ G,
    float* __restrict__ Gnext, float ca, float cb, float cc, int last,
    unsigned short* __restrict__ WT2){
  __shared__ float wr[2][256], yl[2][256];
  const int t = threadIdx.x;
  const int c = t & 255, row = t >> 8;
  const int r = blockIdx.x * 2 + row;
  wr[row][c] = W[(size_t)r * 256 + c];
  __syncthreads();
  float y = 0;
  #pragma unroll 8
  for (int k = 0; k < 256; ++k)
    y = fmaf(wr[row][k], G[(size_t)k * 256 + c], y);
  yl[row][c] = y;
  __syncthreads();
  float d = 0;
  #pragma unroll 8
  for (int k = 0; k < 256; ++k)
    d = fmaf(yl[row][k], G[(size_t)k * 256 + c], d);
  float nw = ca * wr[row][c] + cb * y + cc * d;
  W[(size_t)r * 256 + c] = nw;
  if (r < 256) Gnext[(size_t)r * 256 + c] = 0.0f;
  if (last){
    size_t e = (size_t)(r >> 5) * 8192 + (size_t)((r >> 3) & 3) * 2048 + (size_t)c * 8 + (r & 7);
    WT2[e] = f2bf(nw);
  }
}

// ------- shared-B dbuf GEMM: C[M,256] = A[M,KDIM](f32) * B(bf16 tiles) -------------
// BM=128 (4 waves x 32 rows x 256 cols), BK=32, double-buffered LDS for A and B.
// B staged verbatim via global_load_lds (shared across waves -> B traffic/CU = A
// traffic). A reg-staged fp32 -> bf16 with XOR slot swizzle (conflict-free reads).
// 2 blocks/CU (grid 512 at KS=8) so one block computes while the other drains.
// EPI==0: bf16 output in B tile format (KS must be 1)
// EPI==1: fp32 partial per kp -> Cout + kp*8192*256

template<int KDIM, int KS, int EPI>
__global__ __launch_bounds__(256) void kgemmS(const float* __restrict__ A,
    const unsigned short* __restrict__ B, void* __restrict__ Cout){
  __shared__ __align__(16) unsigned short As[2][4096];   // 128r x 32k bf16, swizzled (8KB)
  __shared__ __align__(16) unsigned short Bs[2][8192];   // 16KB B tile

  const int t = threadIdx.x;
  const int w = t >> 6, lane = t & 63;
  const int rlo = lane & 15, l16 = lane >> 4;
  const int kp = (KS > 1) ? (int)(blockIdx.x % KS) : 0;  // bid%8 -> XCD-pinned K-slice
  const int rb = (KS > 1) ? (int)(blockIdx.x / KS) : (int)blockIdx.x;
  constexpr int KLOC = KDIM / KS;
  constexpr int NS = KLOC / 32;
  const int kbase = kp * KLOC;

  // A staging: thread covers row t>>1, k-half (t&1)*16 (16 fp32 = 4 float4)
  const int arow = t >> 1, akh = t & 1;
  const float* astg = A + (size_t)(rb * 128 + arow) * KDIM + kbase + akh * 16;
  const int aswz = (arow >> 1) & 3;
  const int ab0 = arow * 64 + ((2 * akh)     ^ aswz) * 16;   // byte offsets in As
  const int ab1 = arow * 64 + ((2 * akh + 1) ^ aswz) * 16;
  // B staging: wave w covers bytes [w*4096, +4096) of the 16KB tile
  const unsigned short* bstg = B + (size_t)(kbase >> 5) * 8192 + w * 2048 + lane * 8;

  f32x4 acc[2][16];
  #pragma unroll
  for (int mf = 0; mf < 2; ++mf)
    #pragma unroll
    for (int nf = 0; nf < 16; ++nf){
      acc[mf][nf][0] = 0.f; acc[mf][nf][1] = 0.f;
      acc[mf][nf][2] = 0.f; acc[mf][nf][3] = 0.f;
    }

  float4 q0, q1, q2, q3;
#define LOADA(S) { const float* p_ = astg + (size_t)(S) * 32; \
    q0 = *reinterpret_cast<const float4*>(p_); \
    q1 = *reinterpret_cast<const float4*>(p_ + 4); \
    q2 = *reinterpret_cast<const float4*>(p_ + 8); \
    q3 = *reinterpret_cast<const float4*>(p_ + 12); }
#define WRITEA(BUF) { char* b_ = reinterpret_cast<char*>(&As[BUF][0]); \
    *reinterpret_cast<bf16x8*>(b_ + ab0) = cvtpack8(q0, q1); \
    *reinterpret_cast<bf16x8*>(b_ + ab1) = cvtpack8(q2, q3); }
#define STAGE_B(BUF, S) { \
    _Pragma("unroll") \
    for (int i = 0; i < 4; ++i) \
      gload16(bstg + (size_t)(S) * 8192 + i * 512, &Bs[BUF][w * 2048 + i * 512]); }
#define COMPUTE(BUF) { \
    bf16x8 afr[2]; \
    const char* ab_ = reinterpret_cast<const char*>(&As[BUF][0]); \
    _Pragma("unroll") \
    for (int mf = 0; mf < 2; ++mf){ \
      int row = w * 32 + mf * 16 + rlo; \
      afr[mf] = *reinterpret_cast<const bf16x8*>( \
          ab_ + row * 64 + ((l16 ^ ((row >> 1) & 3)) * 16)); \
    } \
    _Pragma("unroll") \
    for (int nf = 0; nf < 16; ++nf){ \
      bf16x8 bf_ = *reinterpret_cast<const bf16x8*>(&Bs[BUF][l16 * 2048 + (nf * 16 + rlo) * 8]); \
      acc[0][nf] = __builtin_amdgcn_mfma_f32_16x16x32_bf16(afr[0], bf_, acc[0][nf], 0, 0, 0); \
      acc[1][nf] = __builtin_amdgcn_mfma_f32_16x16x32_bf16(afr[1], bf_, acc[1][nf], 0, 0, 0); \
    } }

  // prologue: stage tile 0
  STAGE_B(0, 0);
  LOADA(0);
  WRITEA(0);
  __syncthreads();

  #pragma unroll 1
  for (int s = 0; s < NS; ++s){
    const int cur = s & 1;
    if (s + 1 < NS){ STAGE_B(cur ^ 1, s + 1); LOADA(s + 1); }
    COMPUTE(cur);
    if (s + 1 < NS) WRITEA(cur ^ 1);
    __syncthreads();
  }
#undef LOADA
#undef WRITEA
#undef STAGE_B
#undef COMPUTE

  if constexpr (EPI == 0){
    unsigned short* H = reinterpret_cast<unsigned short*>(Cout);
    #pragma unroll
    for (int mf = 0; mf < 2; ++mf)
      #pragma unroll
      for (int nf = 0; nf < 16; ++nf){
        int c  = nf * 16 + rlo;
        int m0 = rb * 128 + w * 32 + mf * 16 + (l16 << 2);
        size_t e = (size_t)(m0 >> 5) * 8192 + (size_t)((m0 >> 3) & 3) * 2048
                 + (size_t)c * 8 + (m0 & 7);
        union { bf16x4 v; unsigned short u[4]; } p;
        p.u[0] = f2bf(acc[mf][nf][0]);
        p.u[1] = f2bf(acc[mf][nf][1]);
        p.u[2] = f2bf(acc[mf][nf][2]);
        p.u[3] = f2bf(acc[mf][nf][3]);
        *reinterpret_cast<bf16x4*>(&H[e]) = p.v;
      }
  } else {
    float* O = reinterpret_cast<float*>(Cout) + (size_t)kp * 8192 * 256;
    #pragma unroll
    for (int mf = 0; mf < 2; ++mf)
      #pragma unroll
      for (int nf = 0; nf < 16; ++nf){
        int c  = nf * 16 + rlo;
        int m0 = rb * 128 + w * 32 + mf * 16 + (l16 << 2);
        #pragma unroll
        for (int j = 0; j < 4; ++j)
          O[(size_t)(m0 + j) * 256 + c] = acc[mf][nf][j];
      }
  }
}

// out = relu(sum of 8 partials), float4-vectorized
__global__ __launch_bounds__(256) void kreduce8(const float* __restrict__ P, float* __restrict__ O){
  size_t i = (size_t)blockIdx.x * 256 + threadIdx.x;
  const float4* p = reinterpret_cast<const float4*>(P);
  float4 r = p[i];
  #pragma unroll
  for (int q = 1; q < 8; ++q){
    float4 b = p[i + (size_t)q * 524288];
    r.x += b.x; r.y += b.y; r.z += b.z; r.w += b.w;
  }
  r.x = fmaxf(r.x, 0.f); r.y = fmaxf(r.y, 0.f);
  r.z = fmaxf(r.z, 0.f); r.w = fmaxf(r.w, 0.f);
  reinterpret_cast<float4*>(O)[i] = r;
}

// ---------------- launcher ----------------

extern "C" void kernel_launch(void* const* d_in, const int* in_sizes, int n_in,
                              void* d_out, int out_size, void* d_ws, size_t ws_size,
                              hipStream_t stream) {
  const float* x   = (const float*)d_in[0];   // [8192,512]
  const float* adj = (const float*)d_in[1];   // [8192,8192]
  const float* wt  = (const float*)d_in[2];   // [256,512]
  float* out = (float*)d_out;                 // [8192,256]

  char* ws = (char*)d_ws;
  float* n2            = (float*)ws;                                    // 4 B
  float* W             = (float*)(ws + 4096);                           // 512 KB
  float* G0            = (float*)(ws + 4096 + 524288);                  // 256 KB
  float* G1            = (float*)(ws + 4096 + 524288 + 262144);         // 256 KB
  unsigned short* WT2  = (unsigned short*)(ws + 4096 + 524288 + 2*262144);   // 256 KB
  unsigned short* HT2  = (unsigned short*)(ws + 4096 + 524288 + 3*262144);   // 4 MB
  float* Cpart         = (float*)(ws + 4096 + 524288 + 3*262144 + 4194304);  // 64 MB

  kzero<<<257, 256, 0, stream>>>(G0, n2);
  knorm<<<128, 256, 0, stream>>>(wt, n2);
  kinit<<<256, 256, 0, stream>>>(wt, n2, W);

  // 4 iterations: aggressive quintic, Muon quintic, 2 exact Bjorck steps
  const float ca[4] = { 4.2000f, 3.4445f, 1.875f, 1.875f };
  const float cb[4] = {-9.0000f, -4.7750f, -1.25f, -1.25f };
  const float cc[4] = {-6.8000f, 2.0315f, 0.375f, 0.375f };
  float* Gb[2] = {G0, G1};
  for (int it = 0; it < 4; ++it){
    float* Gc = Gb[it & 1];
    float* Gn = Gb[(it + 1) & 1];
    kgram2<<<dim3(8, 8, 8), 256, 0, stream>>>(W, Gc);
    kupdate2<<<256, 512, 0, stream>>>(W, Gc, Gn, ca[it], cb[it], cc[it], it == 3 ? 1 : 0, WT2);
  }

  // h (B tile format, bf16) = x @ W    (64 blocks of BM=128)
  kgemmS<512, 1, 0><<<64, 256, 0, stream>>>(x, WT2, (void*)HT2);
  // partials: Cpart[kp] = adj[:, kslice] @ h[kslice, :]  (64 rb x 8 kp = 2 blocks/CU)
  kgemmS<8192, 8, 1><<<512, 256, 0, stream>>>(adj, HT2, (void*)Cpart);
  // out = relu(sum partials)
  kreduce8<<<2048, 256, 0, stream>>>(Cpart, out);
}

// Round 10
// 245.707 us; speedup vs baseline: 1.0661x; 1.0661x over previous
//
#include <hip/hip_runtime.h>

typedef __attribute__((ext_vector_type(8))) short bf16x8;
typedef __attribute__((ext_vector_type(4))) short bf16x4;
typedef __attribute__((ext_vector_type(4))) float f32x4;

__device__ __forceinline__ unsigned short f2bf(float x){
  unsigned u = __float_as_uint(x);
  u = (u + 0x7fffu + ((u >> 16) & 1u)) >> 16;
  return (unsigned short)u;
}

__device__ __forceinline__ bf16x8 cvtpack8(float4 a, float4 b){
  union { bf16x8 v; unsigned short u[8]; } p;
  p.u[0] = f2bf(a.x); p.u[1] = f2bf(a.y); p.u[2] = f2bf(a.z); p.u[3] = f2bf(a.w);
  p.u[4] = f2bf(b.x); p.u[5] = f2bf(b.y); p.u[6] = f2bf(b.z); p.u[7] = f2bf(b.w);
  return p.v;
}

// async global->LDS, 16B/lane: LDS dest = wave-uniform base + lane*16
__device__ __forceinline__ void gload16(const void* g, void* l){
  __builtin_amdgcn_global_load_lds(
      (const __attribute__((address_space(1))) unsigned int*)g,
      (__attribute__((address_space(3))) unsigned int*)l, 16, 0, 0);
}

// ---- B tile format (bf16): tile sg covers k in [sg*32, sg*32+32), 16KB:
//   elem = sg*8192 + ((k>>3)&3)*2048 + c*8 + (k&7)      (c in [0,256))
// Contiguous per tile -> verbatim global_load_lds staging.

// ---------------- zero init ----------------
__global__ __launch_bounds__(256) void kzero(float* __restrict__ G0, float* __restrict__ n2){
  int b = blockIdx.x;
  if (b < 256) G0[b * 256 + threadIdx.x] = 0.0f;
  else if (threadIdx.x == 0) *n2 = 0.0f;
}

// ---------------- Bjorck (polar factor) small kernels ----------------

__global__ __launch_bounds__(256) void knorm(const float* __restrict__ wt, float* __restrict__ n2){
  int t = blockIdx.x * 256 + threadIdx.x;
  float4 v = reinterpret_cast<const float4*>(wt)[t];
  float s = v.x*v.x + v.y*v.y + v.z*v.z + v.w*v.w;
  #pragma unroll
  for (int o = 32; o > 0; o >>= 1) s += __shfl_down(s, o, 64);
  __shared__ float red[4];
  if ((threadIdx.x & 63) == 0) red[threadIdx.x >> 6] = s;
  __syncthreads();
  if (threadIdx.x == 0) atomicAdd(n2, red[0] + red[1] + red[2] + red[3]);
}

__global__ __launch_bounds__(256) void kinit(const float* __restrict__ wt, const float* __restrict__ n2,
                                             float* __restrict__ W){
  int c = blockIdx.x;
  int r = threadIdx.x;
  float s = rsqrtf(*n2) * (1.0f / 0.3f);
  W[(size_t)r * 256 + c]         = wt[(size_t)c * 512 + r] * s;
  W[(size_t)(r + 256) * 256 + c] = wt[(size_t)c * 512 + r + 256] * s;
}

// G += partial(W^T W): grid (8 j, 8 i, 8 k-parts), 32x32 tile, k-range 64
__global__ __launch_bounds__(256) void kgram2(const float* __restrict__ W, float* __restrict__ G){
  __shared__ __align__(16) float Wi[64][32];
  __shared__ __align__(16) float Wj[64][32];
  const int t = threadIdx.x;
  const int i0 = blockIdx.y * 32, j0 = blockIdx.x * 32, k0 = blockIdx.z * 64;
  const int lr = t >> 3, lc = (t & 7) * 4;
  #pragma unroll
  for (int p = 0; p < 2; ++p){
    int r = lr + p * 32;
    *reinterpret_cast<float4*>(&Wi[r][lc]) =
        *reinterpret_cast<const float4*>(&W[(size_t)(k0 + r) * 256 + i0 + lc]);
    *reinterpret_cast<float4*>(&Wj[r][lc]) =
        *reinterpret_cast<const float4*>(&W[(size_t)(k0 + r) * 256 + j0 + lc]);
  }
  __syncthreads();
  const int tx = t & 31, iy = t >> 5;
  float g0 = 0, g1 = 0, g2 = 0, g3 = 0;
  #pragma unroll 8
  for (int k = 0; k < 64; ++k){
    float wj = Wj[k][tx];
    float4 wi = *reinterpret_cast<const float4*>(&Wi[k][iy * 4]);
    g0 = fmaf(wi.x, wj, g0); g1 = fmaf(wi.y, wj, g1);
    g2 = fmaf(wi.z, wj, g2); g3 = fmaf(wi.w, wj, g3);
  }
  float* gp = &G[(size_t)(i0 + iy * 4) * 256 + j0 + tx];
  atomicAdd(gp,       g0); atomicAdd(gp + 256, g1);
  atomicAdd(gp + 512, g2); atomicAdd(gp + 768, g3);
}

// W <- ca*W + cb*(W G) + cc*(W G) G ; zeroes Gnext; last: emit WT2 in B tile format
__global__ __launch_bounds__(512) void kupdate2(float* __restrict__ W, const float* __restrict__ G,
    float* __restrict__ Gnext, float ca, float cb, float cc, int last,
    unsigned short* __restrict__ WT2){
  __shared__ float wr[2][256], yl[2][256];
  const int t = threadIdx.x;
  const int c = t & 255, row = t >> 8;
  const int r = blockIdx.x * 2 + row;
  wr[row][c] = W[(size_t)r * 256 + c];
  __syncthreads();
  float y = 0;
  #pragma unroll 8
  for (int k = 0; k < 256; ++k)
    y = fmaf(wr[row][k], G[(size_t)k * 256 + c], y);
  yl[row][c] = y;
  __syncthreads();
  float d = 0;
  #pragma unroll 8
  for (int k = 0; k < 256; ++k)
    d = fmaf(yl[row][k], G[(size_t)k * 256 + c], d);
  float nw = ca * wr[row][c] + cb * y + cc * d;
  W[(size_t)r * 256 + c] = nw;
  if (r < 256) Gnext[(size_t)r * 256 + c] = 0.0f;
  if (last){
    size_t e = (size_t)(r >> 5) * 8192 + (size_t)((r >> 3) & 3) * 2048 + (size_t)c * 8 + (r & 7);
    WT2[e] = f2bf(nw);
  }
}

// ------- shared-B dbuf GEMM (small, x@W): BM=128, BK=32, from round 9 (verified) ----
template<int KDIM, int KS, int EPI>
__global__ __launch_bounds__(256) void kgemmS(const float* __restrict__ A,
    const unsigned short* __restrict__ B, void* __restrict__ Cout){
  __shared__ __align__(16) unsigned short As[2][4096];
  __shared__ __align__(16) unsigned short Bs[2][8192];

  const int t = threadIdx.x;
  const int w = t >> 6, lane = t & 63;
  const int rlo = lane & 15, l16 = lane >> 4;
  const int kp = (KS > 1) ? (int)(blockIdx.x % KS) : 0;
  const int rb = (KS > 1) ? (int)(blockIdx.x / KS) : (int)blockIdx.x;
  constexpr int KLOC = KDIM / KS;
  constexpr int NS = KLOC / 32;
  const int kbase = kp * KLOC;

  const int arow = t >> 1, akh = t & 1;
  const float* astg = A + (size_t)(rb * 128 + arow) * KDIM + kbase + akh * 16;
  const int aswz = (arow >> 1) & 3;
  const int ab0 = arow * 64 + ((2 * akh)     ^ aswz) * 16;
  const int ab1 = arow * 64 + ((2 * akh + 1) ^ aswz) * 16;
  const unsigned short* bstg = B + (size_t)(kbase >> 5) * 8192 + w * 2048 + lane * 8;

  f32x4 acc[2][16];
  #pragma unroll
  for (int mf = 0; mf < 2; ++mf)
    #pragma unroll
    for (int nf = 0; nf < 16; ++nf){
      acc[mf][nf][0] = 0.f; acc[mf][nf][1] = 0.f;
      acc[mf][nf][2] = 0.f; acc[mf][nf][3] = 0.f;
    }

  float4 q0, q1, q2, q3;
#define LOADA(S) { const float* p_ = astg + (size_t)(S) * 32; \
    q0 = *reinterpret_cast<const float4*>(p_); \
    q1 = *reinterpret_cast<const float4*>(p_ + 4); \
    q2 = *reinterpret_cast<const float4*>(p_ + 8); \
    q3 = *reinterpret_cast<const float4*>(p_ + 12); }
#define WRITEA(BUF) { char* b_ = reinterpret_cast<char*>(&As[BUF][0]); \
    *reinterpret_cast<bf16x8*>(b_ + ab0) = cvtpack8(q0, q1); \
    *reinterpret_cast<bf16x8*>(b_ + ab1) = cvtpack8(q2, q3); }
#define STAGE_B(BUF, S) { \
    _Pragma("unroll") \
    for (int i = 0; i < 4; ++i) \
      gload16(bstg + (size_t)(S) * 8192 + i * 512, &Bs[BUF][w * 2048 + i * 512]); }
#define COMPUTE(BUF) { \
    bf16x8 afr[2]; \
    const char* ab_ = reinterpret_cast<const char*>(&As[BUF][0]); \
    _Pragma("unroll") \
    for (int mf = 0; mf < 2; ++mf){ \
      int row = w * 32 + mf * 16 + rlo; \
      afr[mf] = *reinterpret_cast<const bf16x8*>( \
          ab_ + row * 64 + ((l16 ^ ((row >> 1) & 3)) * 16)); \
    } \
    _Pragma("unroll") \
    for (int nf = 0; nf < 16; ++nf){ \
      bf16x8 bf_ = *reinterpret_cast<const bf16x8*>(&Bs[BUF][l16 * 2048 + (nf * 16 + rlo) * 8]); \
      acc[0][nf] = __builtin_amdgcn_mfma_f32_16x16x32_bf16(afr[0], bf_, acc[0][nf], 0, 0, 0); \
      acc[1][nf] = __builtin_amdgcn_mfma_f32_16x16x32_bf16(afr[1], bf_, acc[1][nf], 0, 0, 0); \
    } }

  STAGE_B(0, 0);
  LOADA(0);
  WRITEA(0);
  __syncthreads();

  #pragma unroll 1
  for (int s = 0; s < NS; ++s){
    const int cur = s & 1;
    if (s + 1 < NS){ STAGE_B(cur ^ 1, s + 1); LOADA(s + 1); }
    COMPUTE(cur);
    if (s + 1 < NS) WRITEA(cur ^ 1);
    __syncthreads();
  }
#undef LOADA
#undef WRITEA
#undef STAGE_B
#undef COMPUTE

  if constexpr (EPI == 0){
    unsigned short* H = reinterpret_cast<unsigned short*>(Cout);
    #pragma unroll
    for (int mf = 0; mf < 2; ++mf)
      #pragma unroll
      for (int nf = 0; nf < 16; ++nf){
        int c  = nf * 16 + rlo;
        int m0 = rb * 128 + w * 32 + mf * 16 + (l16 << 2);
        size_t e = (size_t)(m0 >> 5) * 8192 + (size_t)((m0 >> 3) & 3) * 2048
                 + (size_t)c * 8 + (m0 & 7);
        union { bf16x4 v; unsigned short u[4]; } p;
        p.u[0] = f2bf(acc[mf][nf][0]);
        p.u[1] = f2bf(acc[mf][nf][1]);
        p.u[2] = f2bf(acc[mf][nf][2]);
        p.u[3] = f2bf(acc[mf][nf][3]);
        *reinterpret_cast<bf16x4*>(&H[e]) = p.v;
      }
  } else {
    float* O = reinterpret_cast<float*>(Cout) + (size_t)kp * 8192 * 256;
    #pragma unroll
    for (int mf = 0; mf < 2; ++mf)
      #pragma unroll
      for (int nf = 0; nf < 16; ++nf){
        int c  = nf * 16 + rlo;
        int m0 = rb * 128 + w * 32 + mf * 16 + (l16 << 2);
        #pragma unroll
        for (int j = 0; j < 4; ++j)
          O[(size_t)(m0 + j) * 256 + c] = acc[mf][nf][j];
      }
  }
}

// ------- BIG GEMM, m201-style counted-vmcnt pipeline -------------------------------
// C[8192,256] partials = adj[8192, kslice] * h[kslice, 256]
// BM=256 (8 waves = 2x4), BK=32, triple-buffered LDS: A fp32 32KB + B bf16 16KB per
// stage (144KB total), depth-2 cluster lookahead, vmcnt(6)+barrier per step.
// A fp32 tile [256r][32k] with 16B-slot XOR swizzle (slot ^= row&7), source
// pre-swizzled so DMA dest stays linear. B in 32-k tile format (verbatim DMA).
template<int KDIM, int KS>
__global__ __launch_bounds__(512, 1) void kgemmB(const float* __restrict__ A,
    const unsigned short* __restrict__ B, float* __restrict__ Cout){
  __shared__ __align__(16) float          As[3][8192];   // 3 x 32KB
  __shared__ __align__(16) unsigned short Bs[3][8192];   // 3 x 16KB

  const int t = threadIdx.x;
  const int w = t >> 6, lane = t & 63;
  const int rlo = lane & 15, l16 = lane >> 4;
  const int wr = w >> 2, wc = w & 3;
  const int kp = (int)(blockIdx.x % KS);        // XCD-pinned K-slice
  const int rb = (int)(blockIdx.x / KS);
  constexpr int KLOC = KDIM / KS;
  constexpr int NT = KLOC / 32;
  const int kbase = kp * KLOC;

  // A staging: instr i, lane l -> row w*32+i*8+(l>>3), 16B of k-slot ((l&7)^(l>>3))
  const int srow = lane >> 3;                    // 0..7
  const int sslot = (lane & 7) ^ srow;           // pre-swizzled source slot
  const float* astg = A + (size_t)(rb * 256 + w * 32 + srow) * KDIM + kbase + sslot * 4;
  // B staging: wave w covers elements [w*1024, +1024) of the 16KB tile
  const unsigned short* bstg = B + (size_t)(kbase >> 5) * 8192 + w * 1024 + lane * 8;

  f32x4 acc[8][4];
  #pragma unroll
  for (int mf = 0; mf < 8; ++mf)
    #pragma unroll
    for (int nf = 0; nf < 4; ++nf){
      acc[mf][nf][0] = 0.f; acc[mf][nf][1] = 0.f;
      acc[mf][nf][2] = 0.f; acc[mf][nf][3] = 0.f;
    }

#define STAGEK(bi, st) { \
    _Pragma("unroll") \
    for (int i = 0; i < 4; ++i) \
      gload16(astg + (size_t)(st) * 32 + (size_t)i * 8 * KDIM, \
              &As[bi][(w * 32 + i * 8) * 32]); \
    _Pragma("unroll") \
    for (int i = 0; i < 2; ++i) \
      gload16(bstg + (size_t)(st) * 8192 + i * 512, &Bs[bi][w * 1024 + i * 512]); }

#define COMPUTEK(bi) { \
    bf16x8 bfr[4]; \
    _Pragma("unroll") \
    for (int nf = 0; nf < 4; ++nf) \
      bfr[nf] = *reinterpret_cast<const bf16x8*>( \
          &Bs[bi][l16 * 2048 + (wc * 64 + nf * 16 + rlo) * 8]); \
    _Pragma("unroll") \
    for (int mf = 0; mf < 8; ++mf){ \
      int R = wr * 128 + mf * 16 + rlo; \
      int s0 = (l16 * 2) ^ (R & 7); \
      int s1 = (l16 * 2 + 1) ^ (R & 7); \
      float4 f0 = *reinterpret_cast<const float4*>(&As[bi][R * 32 + s0 * 4]); \
      float4 f1 = *reinterpret_cast<const float4*>(&As[bi][R * 32 + s1 * 4]); \
      bf16x8 afr = cvtpack8(f0, f1); \
      _Pragma("unroll") \
      for (int nf = 0; nf < 4; ++nf) \
        acc[mf][nf] = __builtin_amdgcn_mfma_f32_16x16x32_bf16(afr, bfr[nf], acc[mf][nf], 0, 0, 0); \
    } }

  // prologue: 2 clusters in flight, wait for the first (vmcnt counts per-wave: 6/cluster)
  STAGEK(0, 0);
  STAGEK(1, 1);
  asm volatile("s_waitcnt vmcnt(6)" ::: "memory");
  __builtin_amdgcn_s_barrier();
  asm volatile("" ::: "memory");

  int cur = 0;
  #pragma unroll 1
  for (int s = 0; s < NT; ++s){
    int nb = cur + 2; if (nb >= 3) nb -= 3;
    int st = (s + 2 < NT) ? s + 2 : NT - 1;     // clamp: keep counts uniform in tail
    STAGEK(nb, st);
    COMPUTEK(cur);
    asm volatile("s_waitcnt vmcnt(6)" ::: "memory");
    __builtin_amdgcn_s_barrier();
    asm volatile("" ::: "memory");
    if (++cur == 3) cur = 0;
  }
#undef STAGEK
#undef COMPUTEK

  float* O = Cout + (size_t)kp * 8192 * 256;
  #pragma unroll
  for (int mf = 0; mf < 8; ++mf)
    #pragma unroll
    for (int nf = 0; nf < 4; ++nf){
      int c  = wc * 64 + nf * 16 + rlo;
      int m0 = rb * 256 + wr * 128 + mf * 16 + (l16 << 2);
      #pragma unroll
      for (int j = 0; j < 4; ++j)
        O[(size_t)(m0 + j) * 256 + c] = acc[mf][nf][j];
    }
}

// out = relu(sum of 8 partials), float4-vectorized
__global__ __launch_bounds__(256) void kreduce8(const float* __restrict__ P, float* __restrict__ O){
  size_t i = (size_t)blockIdx.x * 256 + threadIdx.x;
  const float4* p = reinterpret_cast<const float4*>(P);
  float4 r = p[i];
  #pragma unroll
  for (int q = 1; q < 8; ++q){
    float4 b = p[i + (size_t)q * 524288];
    r.x += b.x; r.y += b.y; r.z += b.z; r.w += b.w;
  }
  r.x = fmaxf(r.x, 0.f); r.y = fmaxf(r.y, 0.f);
  r.z = fmaxf(r.z, 0.f); r.w = fmaxf(r.w, 0.f);
  reinterpret_cast<float4*>(O)[i] = r;
}

// ---------------- launcher ----------------

extern "C" void kernel_launch(void* const* d_in, const int* in_sizes, int n_in,
                              void* d_out, int out_size, void* d_ws, size_t ws_size,
                              hipStream_t stream) {
  const float* x   = (const float*)d_in[0];   // [8192,512]
  const float* adj = (const float*)d_in[1];   // [8192,8192]
  const float* wt  = (const float*)d_in[2];   // [256,512]
  float* out = (float*)d_out;                 // [8192,256]

  char* ws = (char*)d_ws;
  float* n2            = (float*)ws;                                    // 4 B
  float* W             = (float*)(ws + 4096);                           // 512 KB
  float* G0            = (float*)(ws + 4096 + 524288);                  // 256 KB
  float* G1            = (float*)(ws + 4096 + 524288 + 262144);         // 256 KB
  unsigned short* WT2  = (unsigned short*)(ws + 4096 + 524288 + 2*262144);   // 256 KB
  unsigned short* HT2  = (unsigned short*)(ws + 4096 + 524288 + 3*262144);   // 4 MB
  float* Cpart         = (float*)(ws + 4096 + 524288 + 3*262144 + 4194304);  // 64 MB

  kzero<<<257, 256, 0, stream>>>(G0, n2);
  knorm<<<128, 256, 0, stream>>>(wt, n2);
  kinit<<<256, 256, 0, stream>>>(wt, n2, W);

  // 4 iterations: aggressive quintic, Muon quintic, 2 exact Bjorck steps
  const float ca[4] = { 4.2000f, 3.4445f, 1.875f, 1.875f };
  const float cb[4] = {-9.0000f, -4.7750f, -1.25f, -1.25f };
  const float cc[4] = {-6.8000f, 2.0315f, 0.375f, 0.375f };
  float* Gb[2] = {G0, G1};
  for (int it = 0; it < 4; ++it){
    float* Gc = Gb[it & 1];
    float* Gn = Gb[(it + 1) & 1];
    kgram2<<<dim3(8, 8, 8), 256, 0, stream>>>(W, Gc);
    kupdate2<<<256, 512, 0, stream>>>(W, Gc, Gn, ca[it], cb[it], cc[it], it == 3 ? 1 : 0, WT2);
  }

  // h (B tile format, bf16) = x @ W    (64 blocks of BM=128)
  kgemmS<512, 1, 0><<<64, 256, 0, stream>>>(x, WT2, (void*)HT2);
  // partials: Cpart[kp] = adj[:, kslice] @ h[kslice, :]  (32 rb x 8 kp = 1 block/CU)
  kgemmB<8192, 8><<<256, 512, 0, stream>>>(adj, HT2, Cpart);
  // out = relu(sum partials)
  kreduce8<<<2048, 256, 0, stream>>>(Cpart, out);
}

// Round 11
// 238.061 us; speedup vs baseline: 1.1003x; 1.0321x over previous
//
#include <hip/hip_runtime.h>

typedef __attribute__((ext_vector_type(8))) short bf16x8;
typedef __attribute__((ext_vector_type(4))) short bf16x4;
typedef __attribute__((ext_vector_type(4))) float f32x4;

__device__ __forceinline__ unsigned short f2bf(float x){
  unsigned u = __float_as_uint(x);
  u = (u + 0x7fffu + ((u >> 16) & 1u)) >> 16;
  return (unsigned short)u;
}

__device__ __forceinline__ bf16x8 cvtpack8(float4 a, float4 b){
  union { bf16x8 v; unsigned short u[8]; } p;
  p.u[0] = f2bf(a.x); p.u[1] = f2bf(a.y); p.u[2] = f2bf(a.z); p.u[3] = f2bf(a.w);
  p.u[4] = f2bf(b.x); p.u[5] = f2bf(b.y); p.u[6] = f2bf(b.z); p.u[7] = f2bf(b.w);
  return p.v;
}

// async global->LDS, 16B/lane: LDS dest = wave-uniform base + lane*16
__device__ __forceinline__ void gload16(const void* g, void* l){
  __builtin_amdgcn_global_load_lds(
      (const __attribute__((address_space(1))) unsigned int*)g,
      (__attribute__((address_space(3))) unsigned int*)l, 16, 0, 0);
}

// ---- B tile format (bf16): tile sg covers k in [sg*32, sg*32+32), 16KB:
//   elem = sg*8192 + ((k>>3)&3)*2048 + c*8 + (k&7)      (c in [0,256))
// Contiguous per tile -> verbatim global_load_lds staging; fragment ds_read_b128
// at consecutive c is consecutive-address (conflict-free).

// ---------------- zero init ----------------
__global__ __launch_bounds__(256) void kzero(float* __restrict__ G0, float* __restrict__ n2){
  int b = blockIdx.x;
  if (b < 256) G0[b * 256 + threadIdx.x] = 0.0f;
  else if (threadIdx.x == 0) *n2 = 0.0f;
}

// ---------------- Bjorck (polar factor) small kernels ----------------

__global__ __launch_bounds__(256) void knorm(const float* __restrict__ wt, float* __restrict__ n2){
  int t = blockIdx.x * 256 + threadIdx.x;
  float4 v = reinterpret_cast<const float4*>(wt)[t];
  float s = v.x*v.x + v.y*v.y + v.z*v.z + v.w*v.w;
  #pragma unroll
  for (int o = 32; o > 0; o >>= 1) s += __shfl_down(s, o, 64);
  __shared__ float red[4];
  if ((threadIdx.x & 63) == 0) red[threadIdx.x >> 6] = s;
  __syncthreads();
  if (threadIdx.x == 0) atomicAdd(n2, red[0] + red[1] + red[2] + red[3]);
}

__global__ __launch_bounds__(256) void kinit(const float* __restrict__ wt, const float* __restrict__ n2,
                                             float* __restrict__ W){
  int c = blockIdx.x;
  int r = threadIdx.x;
  float s = rsqrtf(*n2) * (1.0f / 0.3f);
  W[(size_t)r * 256 + c]         = wt[(size_t)c * 512 + r] * s;
  W[(size_t)(r + 256) * 256 + c] = wt[(size_t)c * 512 + r + 256] * s;
}

// G += partial(W^T W): grid (8 j, 8 i, 8 k-parts), 32x32 tile, k-range 64
__global__ __launch_bounds__(256) void kgram2(const float* __restrict__ W, float* __restrict__ G){
  __shared__ __align__(16) float Wi[64][32];
  __shared__ __align__(16) float Wj[64][32];
  const int t = threadIdx.x;
  const int i0 = blockIdx.y * 32, j0 = blockIdx.x * 32, k0 = blockIdx.z * 64;
  const int lr = t >> 3, lc = (t & 7) * 4;
  #pragma unroll
  for (int p = 0; p < 2; ++p){
    int r = lr + p * 32;
    *reinterpret_cast<float4*>(&Wi[r][lc]) =
        *reinterpret_cast<const float4*>(&W[(size_t)(k0 + r) * 256 + i0 + lc]);
    *reinterpret_cast<float4*>(&Wj[r][lc]) =
        *reinterpret_cast<const float4*>(&W[(size_t)(k0 + r) * 256 + j0 + lc]);
  }
  __syncthreads();
  const int tx = t & 31, iy = t >> 5;
  float g0 = 0, g1 = 0, g2 = 0, g3 = 0;
  #pragma unroll 8
  for (int k = 0; k < 64; ++k){
    float wj = Wj[k][tx];
    float4 wi = *reinterpret_cast<const float4*>(&Wi[k][iy * 4]);
    g0 = fmaf(wi.x, wj, g0); g1 = fmaf(wi.y, wj, g1);
    g2 = fmaf(wi.z, wj, g2); g3 = fmaf(wi.w, wj, g3);
  }
  float* gp = &G[(size_t)(i0 + iy * 4) * 256 + j0 + tx];
  atomicAdd(gp,       g0); atomicAdd(gp + 256, g1);
  atomicAdd(gp + 512, g2); atomicAdd(gp + 768, g3);
}

// W <- ca*W + cb*(W G) + cc*(W G) G ; zeroes Gnext; last: emit WT2 in B tile format
__global__ __launch_bounds__(512) void kupdate2(float* __restrict__ W, const float* __restrict__ G,
    float* __restrict__ Gnext, float ca, float cb, float cc, int last,
    unsigned short* __restrict__ WT2){
  __shared__ float wr[2][256], yl[2][256];
  const int t = threadIdx.x;
  const int c = t & 255, row = t >> 8;
  const int r = blockIdx.x * 2 + row;
  wr[row][c] = W[(size_t)r * 256 + c];
  __syncthreads();
  float y = 0;
  #pragma unroll 8
  for (int k = 0; k < 256; ++k)
    y = fmaf(wr[row][k], G[(size_t)k * 256 + c], y);
  yl[row][c] = y;
  __syncthreads();
  float d = 0;
  #pragma unroll 8
  for (int k = 0; k < 256; ++k)
    d = fmaf(yl[row][k], G[(size_t)k * 256 + c], d);
  float nw = ca * wr[row][c] + cb * y + cc * d;
  W[(size_t)r * 256 + c] = nw;
  if (r < 256) Gnext[(size_t)r * 256 + c] = 0.0f;
  if (last){
    size_t e = (size_t)(r >> 5) * 8192 + (size_t)((r >> 3) & 3) * 2048 + (size_t)c * 8 + (r & 7);
    WT2[e] = f2bf(nw);
  }
}

// ------- shared-B dbuf GEMM (small, x@W): BM=128, BK=32 (round-9 verified) ---------
template<int KDIM, int KS, int EPI>
__global__ __launch_bounds__(256) void kgemmS(const float* __restrict__ A,
    const unsigned short* __restrict__ B, void* __restrict__ Cout){
  __shared__ __align__(16) unsigned short As[2][4096];
  __shared__ __align__(16) unsigned short Bs[2][8192];

  const int t = threadIdx.x;
  const int w = t >> 6, lane = t & 63;
  const int rlo = lane & 15, l16 = lane >> 4;
  const int kp = (KS > 1) ? (int)(blockIdx.x % KS) : 0;
  const int rb = (KS > 1) ? (int)(blockIdx.x / KS) : (int)blockIdx.x;
  constexpr int KLOC = KDIM / KS;
  constexpr int NS = KLOC / 32;
  const int kbase = kp * KLOC;

  const int arow = t >> 1, akh = t & 1;
  const float* astg = A + (size_t)(rb * 128 + arow) * KDIM + kbase + akh * 16;
  const int aswz = (arow >> 1) & 3;
  const int ab0 = arow * 64 + ((2 * akh)     ^ aswz) * 16;
  const int ab1 = arow * 64 + ((2 * akh + 1) ^ aswz) * 16;
  const unsigned short* bstg = B + (size_t)(kbase >> 5) * 8192 + w * 2048 + lane * 8;

  f32x4 acc[2][16];
  #pragma unroll
  for (int mf = 0; mf < 2; ++mf)
    #pragma unroll
    for (int nf = 0; nf < 16; ++nf){
      acc[mf][nf][0] = 0.f; acc[mf][nf][1] = 0.f;
      acc[mf][nf][2] = 0.f; acc[mf][nf][3] = 0.f;
    }

  float4 q0, q1, q2, q3;
#define LOADA(S) { const float* p_ = astg + (size_t)(S) * 32; \
    q0 = *reinterpret_cast<const float4*>(p_); \
    q1 = *reinterpret_cast<const float4*>(p_ + 4); \
    q2 = *reinterpret_cast<const float4*>(p_ + 8); \
    q3 = *reinterpret_cast<const float4*>(p_ + 12); }
#define WRITEA(BUF) { char* b_ = reinterpret_cast<char*>(&As[BUF][0]); \
    *reinterpret_cast<bf16x8*>(b_ + ab0) = cvtpack8(q0, q1); \
    *reinterpret_cast<bf16x8*>(b_ + ab1) = cvtpack8(q2, q3); }
#define STAGE_B(BUF, S) { \
    _Pragma("unroll") \
    for (int i = 0; i < 4; ++i) \
      gload16(bstg + (size_t)(S) * 8192 + i * 512, &Bs[BUF][w * 2048 + i * 512]); }
#define COMPUTE(BUF) { \
    bf16x8 afr[2]; \
    const char* ab_ = reinterpret_cast<const char*>(&As[BUF][0]); \
    _Pragma("unroll") \
    for (int mf = 0; mf < 2; ++mf){ \
      int row = w * 32 + mf * 16 + rlo; \
      afr[mf] = *reinterpret_cast<const bf16x8*>( \
          ab_ + row * 64 + ((l16 ^ ((row >> 1) & 3)) * 16)); \
    } \
    _Pragma("unroll") \
    for (int nf = 0; nf < 16; ++nf){ \
      bf16x8 bf_ = *reinterpret_cast<const bf16x8*>(&Bs[BUF][l16 * 2048 + (nf * 16 + rlo) * 8]); \
      acc[0][nf] = __builtin_amdgcn_mfma_f32_16x16x32_bf16(afr[0], bf_, acc[0][nf], 0, 0, 0); \
      acc[1][nf] = __builtin_amdgcn_mfma_f32_16x16x32_bf16(afr[1], bf_, acc[1][nf], 0, 0, 0); \
    } }

  STAGE_B(0, 0);
  LOADA(0);
  WRITEA(0);
  __syncthreads();

  #pragma unroll 1
  for (int s = 0; s < NS; ++s){
    const int cur = s & 1;
    if (s + 1 < NS){ STAGE_B(cur ^ 1, s + 1); LOADA(s + 1); }
    COMPUTE(cur);
    if (s + 1 < NS) WRITEA(cur ^ 1);
    __syncthreads();
  }
#undef LOADA
#undef WRITEA
#undef STAGE_B
#undef COMPUTE

  if constexpr (EPI == 0){
    unsigned short* H = reinterpret_cast<unsigned short*>(Cout);
    #pragma unroll
    for (int mf = 0; mf < 2; ++mf)
      #pragma unroll
      for (int nf = 0; nf < 16; ++nf){
        int c  = nf * 16 + rlo;
        int m0 = rb * 128 + w * 32 + mf * 16 + (l16 << 2);
        size_t e = (size_t)(m0 >> 5) * 8192 + (size_t)((m0 >> 3) & 3) * 2048
                 + (size_t)c * 8 + (m0 & 7);
        union { bf16x4 v; unsigned short u[4]; } p;
        p.u[0] = f2bf(acc[mf][nf][0]);
        p.u[1] = f2bf(acc[mf][nf][1]);
        p.u[2] = f2bf(acc[mf][nf][2]);
        p.u[3] = f2bf(acc[mf][nf][3]);
        *reinterpret_cast<bf16x4*>(&H[e]) = p.v;
      }
  } else {
    float* O = reinterpret_cast<float*>(Cout) + (size_t)kp * 8192 * 256;
    #pragma unroll
    for (int mf = 0; mf < 2; ++mf)
      #pragma unroll
      for (int nf = 0; nf < 16; ++nf){
        int c  = nf * 16 + rlo;
        int m0 = rb * 128 + w * 32 + mf * 16 + (l16 << 2);
        #pragma unroll
        for (int j = 0; j < 4; ++j)
          O[(size_t)(m0 + j) * 256 + c] = acc[mf][nf][j];
      }
  }
}

// ------- BIG GEMM: traffic-minimal, proven mechanics -------------------------------
// C partials[8192,256] = adj[8192, kslice] * h[kslice, 256]
// BM=256: 8 waves x 32 rows x full 256 cols. A: global->reg in MFMA layout (R6
// mechanics: 4-lane groups cover full 128B lines, zero LDS). B: 16KB k-tile staged
// ONCE per block via global_load_lds, triple-buffered; fragment ds_reads are
// consecutive-address (conflict-free). Depth-2 pipeline both streams; per step a
// wave issues 4 A-loads then 2 B-DMA; vmcnt(6) retires exactly the step-(s+1)
// cluster and keeps step-(s+2) in flight. Tail clamp-issues to keep counts uniform.
template<int KDIM, int KS>
__global__ __launch_bounds__(512) void kgemmF(const float* __restrict__ A,
    const unsigned short* __restrict__ B, float* __restrict__ Cout){
  __shared__ __align__(16) unsigned short Bs[3][8192];   // 3 x 16KB B tiles

  const int t = threadIdx.x;
  const int w = t >> 6, lane = t & 63;
  const int rlo = lane & 15, l16 = lane >> 4;
  const int kp = (int)(blockIdx.x % KS);        // bid%8 -> XCD-pinned K-slice
  const int rb = (int)(blockIdx.x / KS);
  constexpr int KLOC = KDIM / KS;
  constexpr int NS = KLOC / 32;
  const int kbase = kp * KLOC;

  const int row0 = rb * 256 + w * 32 + rlo;
  const float* a0 = A + (size_t)row0 * KDIM + kbase + l16 * 8;
  const float* a1 = a0 + (size_t)16 * KDIM;
  const unsigned short* bstg = B + (size_t)(kbase >> 5) * 8192 + w * 1024 + lane * 8;

  f32x4 acc[2][16];
  #pragma unroll
  for (int mf = 0; mf < 2; ++mf)
    #pragma unroll
    for (int nf = 0; nf < 16; ++nf){
      acc[mf][nf][0] = 0.f; acc[mf][nf][1] = 0.f;
      acc[mf][nf][2] = 0.f; acc[mf][nf][3] = 0.f;
    }

#define LDA(Q, S) { const float* pa_ = a0 + (size_t)(S) * 32; \
    const float* pb_ = a1 + (size_t)(S) * 32; \
    Q[0] = *reinterpret_cast<const float4*>(pa_); \
    Q[1] = *reinterpret_cast<const float4*>(pa_ + 4); \
    Q[2] = *reinterpret_cast<const float4*>(pb_); \
    Q[3] = *reinterpret_cast<const float4*>(pb_ + 4); }
#define STB(BUF, S) { \
    _Pragma("unroll") \
    for (int i = 0; i < 2; ++i) \
      gload16(bstg + (size_t)(S) * 8192 + i * 512, &Bs[BUF][w * 1024 + i * 512]); }
#define STEP(PB, Q, S) { \
    bf16x8 bfr[16]; \
    _Pragma("unroll") \
    for (int nf = 0; nf < 16; ++nf) \
      bfr[nf] = *reinterpret_cast<const bf16x8*>(&Bs[PB][l16 * 2048 + (nf * 16 + rlo) * 8]); \
    bf16x8 afr0 = cvtpack8(Q[0], Q[1]); \
    bf16x8 afr1 = cvtpack8(Q[2], Q[3]); \
    { int st_ = ((S) + 2 < NS) ? (S) + 2 : NS - 1; \
      int pn_ = (PB) + 2; if (pn_ >= 3) pn_ -= 3; \
      LDA(Q, st_); \
      STB(pn_, st_); } \
    _Pragma("unroll") \
    for (int nf = 0; nf < 16; ++nf){ \
      acc[0][nf] = __builtin_amdgcn_mfma_f32_16x16x32_bf16(afr0, bfr[nf], acc[0][nf], 0, 0, 0); \
      acc[1][nf] = __builtin_amdgcn_mfma_f32_16x16x32_bf16(afr1, bfr[nf], acc[1][nf], 0, 0, 0); \
    } \
    asm volatile("s_waitcnt vmcnt(6)" ::: "memory"); \
    __builtin_amdgcn_s_barrier(); \
    asm volatile("" ::: "memory"); }

  float4 q0[4], q1[4];
  // prologue: B(0),B(1),A(0),A(1) in flight; retire B(0),B(1),A(0), keep A(1)
  STB(0, 0);
  STB(1, 1);
  LDA(q0, 0);
  LDA(q1, 1);
  asm volatile("s_waitcnt vmcnt(4)" ::: "memory");
  __builtin_amdgcn_s_barrier();
  asm volatile("" ::: "memory");

  int p = 0;                                // NS even: q0 <-> even steps
  #pragma unroll 1
  for (int s = 0; s < NS; s += 2){
    int p1 = p + 1; if (p1 >= 3) p1 -= 3;
    STEP(p, q0, s);
    STEP(p1, q1, s + 1);
    p = p1 + 1; if (p >= 3) p -= 3;
  }
#undef LDA
#undef STB
#undef STEP

  float* O = Cout + (size_t)kp * 8192 * 256;
  #pragma unroll
  for (int mf = 0; mf < 2; ++mf)
    #pragma unroll
    for (int nf = 0; nf < 16; ++nf){
      int c  = nf * 16 + rlo;
      int m0 = rb * 256 + w * 32 + mf * 16 + (l16 << 2);
      #pragma unroll
      for (int j = 0; j < 4; ++j)
        O[(size_t)(m0 + j) * 256 + c] = acc[mf][nf][j];
    }
}

// out = relu(sum of 8 partials), float4-vectorized
__global__ __launch_bounds__(256) void kreduce8(const float* __restrict__ P, float* __restrict__ O){
  size_t i = (size_t)blockIdx.x * 256 + threadIdx.x;
  const float4* p = reinterpret_cast<const float4*>(P);
  float4 r = p[i];
  #pragma unroll
  for (int q = 1; q < 8; ++q){
    float4 b = p[i + (size_t)q * 524288];
    r.x += b.x; r.y += b.y; r.z += b.z; r.w += b.w;
  }
  r.x = fmaxf(r.x, 0.f); r.y = fmaxf(r.y, 0.f);
  r.z = fmaxf(r.z, 0.f); r.w = fmaxf(r.w, 0.f);
  reinterpret_cast<float4*>(O)[i] = r;
}

// ---------------- launcher ----------------

extern "C" void kernel_launch(void* const* d_in, const int* in_sizes, int n_in,
                              void* d_out, int out_size, void* d_ws, size_t ws_size,
                              hipStream_t stream) {
  const float* x   = (const float*)d_in[0];   // [8192,512]
  const float* adj = (const float*)d_in[1];   // [8192,8192]
  const float* wt  = (const float*)d_in[2];   // [256,512]
  float* out = (float*)d_out;                 // [8192,256]

  char* ws = (char*)d_ws;
  float* n2            = (float*)ws;                                    // 4 B
  float* W             = (float*)(ws + 4096);                           // 512 KB
  float* G0            = (float*)(ws + 4096 + 524288);                  // 256 KB
  float* G1            = (float*)(ws + 4096 + 524288 + 262144);         // 256 KB
  unsigned short* WT2  = (unsigned short*)(ws + 4096 + 524288 + 2*262144);   // 256 KB
  unsigned short* HT2  = (unsigned short*)(ws + 4096 + 524288 + 3*262144);   // 4 MB
  float* Cpart         = (float*)(ws + 4096 + 524288 + 3*262144 + 4194304);  // 64 MB

  kzero<<<257, 256, 0, stream>>>(G0, n2);
  knorm<<<128, 256, 0, stream>>>(wt, n2);
  kinit<<<256, 256, 0, stream>>>(wt, n2, W);

  // 4 iterations: aggressive quintic, Muon quintic, 2 exact Bjorck steps
  const float ca[4] = { 4.2000f, 3.4445f, 1.875f, 1.875f };
  const float cb[4] = {-9.0000f, -4.7750f, -1.25f, -1.25f };
  const float cc[4] = {-6.8000f, 2.0315f, 0.375f, 0.375f };
  float* Gb[2] = {G0, G1};
  for (int it = 0; it < 4; ++it){
    float* Gc = Gb[it & 1];
    float* Gn = Gb[(it + 1) & 1];
    kgram2<<<dim3(8, 8, 8), 256, 0, stream>>>(W, Gc);
    kupdate2<<<256, 512, 0, stream>>>(W, Gc, Gn, ca[it], cb[it], cc[it], it == 3 ? 1 : 0, WT2);
  }

  // h (B tile format, bf16) = x @ W    (64 blocks of BM=128)
  kgemmS<512, 1, 0><<<64, 256, 0, stream>>>(x, WT2, (void*)HT2);
  // partials: Cpart[kp] = adj[:, kslice] @ h[kslice, :]  (32 rb x 8 kp = 1 block/CU)
  kgemmF<8192, 8><<<256, 512, 0, stream>>>(adj, HT2, Cpart);
  // out = relu(sum partials)
  kreduce8<<<2048, 256, 0, stream>>>(Cpart, out);
}